// Round 1
// baseline (278.540 us; speedup 1.0000x reference)
//
#include <hip/hip_runtime.h>

// Problem dims
#define B_SZ 32
#define L_SZ 256
#define D_SZ 512
#define F_SZ 2048
#define E_SZ 8
#define P_SZ 64   // B_SZ * TOP_K
#define BK   32   // K-chunk per MFMA step

typedef __attribute__((ext_vector_type(8))) short bf16x8;
typedef __attribute__((ext_vector_type(4))) float f32x4;

// f32 -> bf16 round-to-nearest-even (finite inputs only)
__device__ __forceinline__ unsigned short f2bf(float f) {
  unsigned int u = __builtin_bit_cast(unsigned int, f);
  u += 0x7fffu + ((u >> 16) & 1u);
  return (unsigned short)(u >> 16);
}

// async global->LDS, 16B per lane; LDS dest is wave-uniform base + lane*16
__device__ __forceinline__ void async16(const void* g, void* l) {
  __builtin_amdgcn_global_load_lds(
      (const __attribute__((address_space(1))) unsigned int*)g,
      (__attribute__((address_space(3))) unsigned int*)l, 16, 0, 0);
}

// ---------------- gates: softmax -> mask -> top2 -> renorm -------------
__global__ void gates_kernel(const float* __restrict__ logits,
                             const int* __restrict__ masks,
                             int* __restrict__ sel_e,
                             float* __restrict__ sel_g) {
  int b = threadIdx.x;
  if (b >= B_SZ) return;
  float lg[E_SZ], p[E_SZ];
  float mx = -1e30f;
  for (int e = 0; e < E_SZ; ++e) { lg[e] = logits[b * E_SZ + e]; mx = fmaxf(mx, lg[e]); }
  float s = 0.f;
  for (int e = 0; e < E_SZ; ++e) { p[e] = expf(lg[e] - mx); s += p[e]; }
  for (int e = 0; e < E_SZ; ++e) p[e] = (masks[b * E_SZ + e] == 1) ? (p[e] / s) : 0.f;
  // top-2, ties -> lower index (strict > replacement), matching lax.top_k
  int i0 = 0, i1 = 1; float v0 = -1.f, v1 = -1.f;
  for (int e = 0; e < E_SZ; ++e) {
    float v = p[e];
    if (v > v0)      { v1 = v0; i1 = i0; v0 = v; i0 = e; }
    else if (v > v1) { v1 = v;  i1 = e; }
  }
  float den = v0 + v1 + 1e-9f;
  sel_e[2 * b]     = i0;  sel_e[2 * b + 1] = i1;
  sel_g[2 * b]     = v0 / den;
  sel_g[2 * b + 1] = v1 / den;
}

// ---------------- f32 -> bf16 (x) -------------------------------------
__global__ void convert_f32_bf16(const float* __restrict__ in,
                                 unsigned short* __restrict__ out, int n4) {
  int i = blockIdx.x * blockDim.x + threadIdx.x;
  if (i >= n4) return;
  float4 v = ((const float4*)in)[i];
  ushort4 o;
  o.x = f2bf(v.x); o.y = f2bf(v.y); o.z = f2bf(v.z); o.w = f2bf(v.w);
  ((ushort4*)out)[i] = o;
}

// ------------- transpose + convert: in [z][R][C] f32 -> out [z][C][R] bf16
__global__ void transpose_convert(const float* __restrict__ in,
                                  unsigned short* __restrict__ out,
                                  int R, int C) {
  __shared__ float tile[64][65];
  const float* ip = in + (size_t)blockIdx.z * R * C;
  unsigned short* op = out + (size_t)blockIdx.z * R * C;
  int c0 = blockIdx.x * 64, r0 = blockIdx.y * 64;
  int tx = threadIdx.x & 63, ty = threadIdx.x >> 6;
#pragma unroll
  for (int i = 0; i < 16; ++i) {
    int r = i * 4 + ty;
    tile[r][tx] = ip[(size_t)(r0 + r) * C + c0 + tx];
  }
  __syncthreads();
#pragma unroll
  for (int i = 0; i < 16; ++i) {
    int rr = i * 4 + ty;  // index along C (output row)
    op[(size_t)(c0 + rr) * R + r0 + tx] = f2bf(tile[tx][rr]);
  }
}

// ------------- stage 1: H[p] = gelu(X_b @ W1[e] + b1[e]) ---------------
// Xb [B][L][D] bf16 ; W1t [E][F][D] bf16 (pre-transposed) ; H [P][L][F] bf16
__global__ __launch_bounds__(256, 2) void moe_gemm1(
    const unsigned short* __restrict__ Xb,
    const unsigned short* __restrict__ W1t,
    const float* __restrict__ b1,
    const int* __restrict__ sel_e,
    unsigned short* __restrict__ H) {
  int p = blockIdx.z;
  int b = p >> 1;
  int e = sel_e[p];
  int f0 = blockIdx.x * 128;
  int l0 = blockIdx.y * 128;

  __shared__ __align__(16) unsigned short As[128 * BK];
  __shared__ __align__(16) unsigned short Bs[128 * BK];

  const unsigned short* Abase = Xb  + ((size_t)b * L_SZ + l0) * D_SZ;
  const unsigned short* Bbase = W1t + ((size_t)e * F_SZ + f0) * D_SZ;

  int tid = threadIdx.x;
  int lane = tid & 63;
  int w = tid >> 6, wm = w & 1, wn = w >> 1;
  int lrow = lane & 15, kg = lane >> 4;

  // staging: 512 16B-segments per tile; wave w does segs w*128+lane, +64
  int seg0 = w * 128 + lane;
  int row0 = seg0 >> 2, ks0 = (seg0 & 3) * 8;
  int seg1 = seg0 + 64;
  int row1 = seg1 >> 2, ks1 = (seg1 & 3) * 8;

  f32x4 acc[4][4] = {};

  for (int k0 = 0; k0 < D_SZ; k0 += BK) {
    async16(Abase + (size_t)row0 * D_SZ + k0 + ks0, &As[seg0 * 8]);
    async16(Abase + (size_t)row1 * D_SZ + k0 + ks1, &As[seg1 * 8]);
    async16(Bbase + (size_t)row0 * D_SZ + k0 + ks0, &Bs[seg0 * 8]);
    async16(Bbase + (size_t)row1 * D_SZ + k0 + ks1, &Bs[seg1 * 8]);
    __syncthreads();
    bf16x8 af[4], bfr[4];
#pragma unroll
    for (int i = 0; i < 4; ++i)
      af[i] = *(const bf16x8*)&As[(wm * 64 + i * 16 + lrow) * BK + kg * 8];
#pragma unroll
    for (int j = 0; j < 4; ++j)
      bfr[j] = *(const bf16x8*)&Bs[(wn * 64 + j * 16 + lrow) * BK + kg * 8];
#pragma unroll
    for (int i = 0; i < 4; ++i)
#pragma unroll
      for (int j = 0; j < 4; ++j)
        acc[i][j] = __builtin_amdgcn_mfma_f32_16x16x32_bf16(af[i], bfr[j], acc[i][j], 0, 0, 0);
    __syncthreads();
  }

  // epilogue: + b1, exact gelu, bf16 store to H
  unsigned short* Hp = H + ((size_t)p * L_SZ + l0) * F_SZ + f0;
  float b1v[4];
#pragma unroll
  for (int j = 0; j < 4; ++j)
    b1v[j] = b1[e * F_SZ + f0 + wn * 64 + j * 16 + lrow];
#pragma unroll
  for (int i = 0; i < 4; ++i) {
    int rbase = wm * 64 + i * 16 + kg * 4;
#pragma unroll
    for (int j = 0; j < 4; ++j) {
      int c = wn * 64 + j * 16 + lrow;
#pragma unroll
      for (int r = 0; r < 4; ++r) {
        float v = acc[i][j][r] + b1v[j];
        v = 0.5f * v * (1.0f + erff(v * 0.70710678118654752f));
        Hp[(size_t)(rbase + r) * F_SZ + c] = f2bf(v);
      }
    }
  }
}

// ------------- stage 2: out[b] = sum_j g_j * (H[p_j] @ W2[e_j]) + gates.b2
// H [P][L][F] bf16 ; W2t [E][D][F] bf16 ; Out [B][L][D] f32
__global__ __launch_bounds__(256, 2) void moe_gemm2(
    const unsigned short* __restrict__ H,
    const unsigned short* __restrict__ W2t,
    const float* __restrict__ b2,
    const int* __restrict__ sel_e,
    const float* __restrict__ sel_g,
    float* __restrict__ Out) {
  int b = blockIdx.z;
  int d0 = blockIdx.x * 128;
  int l0 = blockIdx.y * 128;

  __shared__ __align__(16) unsigned short As[128 * BK];
  __shared__ __align__(16) unsigned short Bs[128 * BK];

  int tid = threadIdx.x;
  int lane = tid & 63;
  int w = tid >> 6, wm = w & 1, wn = w >> 1;
  int lrow = lane & 15, kg = lane >> 4;
  int seg0 = w * 128 + lane;
  int row0 = seg0 >> 2, ks0 = (seg0 & 3) * 8;
  int seg1 = seg0 + 64;
  int row1 = seg1 >> 2, ks1 = (seg1 & 3) * 8;

  float cv[4][4][4] = {};

  for (int jp = 0; jp < 2; ++jp) {
    int p = 2 * b + jp;
    int e = sel_e[p];
    float g = sel_g[p];
    const unsigned short* Abase = H   + ((size_t)p * L_SZ + l0) * F_SZ;
    const unsigned short* Bbase = W2t + ((size_t)e * D_SZ + d0) * F_SZ;
    f32x4 acc[4][4] = {};
    for (int k0 = 0; k0 < F_SZ; k0 += BK) {
      async16(Abase + (size_t)row0 * F_SZ + k0 + ks0, &As[seg0 * 8]);
      async16(Abase + (size_t)row1 * F_SZ + k0 + ks1, &As[seg1 * 8]);
      async16(Bbase + (size_t)row0 * F_SZ + k0 + ks0, &Bs[seg0 * 8]);
      async16(Bbase + (size_t)row1 * F_SZ + k0 + ks1, &Bs[seg1 * 8]);
      __syncthreads();
      bf16x8 af[4], bfr[4];
#pragma unroll
      for (int i = 0; i < 4; ++i)
        af[i] = *(const bf16x8*)&As[(wm * 64 + i * 16 + lrow) * BK + kg * 8];
#pragma unroll
      for (int j = 0; j < 4; ++j)
        bfr[j] = *(const bf16x8*)&Bs[(wn * 64 + j * 16 + lrow) * BK + kg * 8];
#pragma unroll
      for (int i = 0; i < 4; ++i)
#pragma unroll
        for (int j = 0; j < 4; ++j)
          acc[i][j] = __builtin_amdgcn_mfma_f32_16x16x32_bf16(af[i], bfr[j], acc[i][j], 0, 0, 0);
      __syncthreads();
    }
#pragma unroll
    for (int i = 0; i < 4; ++i)
#pragma unroll
      for (int j = 0; j < 4; ++j)
#pragma unroll
        for (int r = 0; r < 4; ++r)
          cv[i][j][r] += g * acc[i][j][r];
  }

  // epilogue: gate-weighted b2 bias, f32 store
  int e0 = sel_e[2 * b], e1 = sel_e[2 * b + 1];
  float g0 = sel_g[2 * b], g1 = sel_g[2 * b + 1];
  float bias[4];
#pragma unroll
  for (int j = 0; j < 4; ++j) {
    int d = d0 + wn * 64 + j * 16 + lrow;
    bias[j] = g0 * b2[e0 * D_SZ + d] + g1 * b2[e1 * D_SZ + d];
  }
  float* Op = Out + ((size_t)b * L_SZ + l0) * D_SZ + d0;
#pragma unroll
  for (int i = 0; i < 4; ++i) {
    int rbase = wm * 64 + i * 16 + kg * 4;
#pragma unroll
    for (int j = 0; j < 4; ++j) {
      int c = wn * 64 + j * 16 + lrow;
#pragma unroll
      for (int r = 0; r < 4; ++r)
        Op[(size_t)(rbase + r) * D_SZ + c] = cv[i][j][r] + bias[j];
    }
  }
}

extern "C" void kernel_launch(void* const* d_in, const int* in_sizes, int n_in,
                              void* d_out, int out_size, void* d_ws, size_t ws_size,
                              hipStream_t stream) {
  const float* x      = (const float*)d_in[0];
  const float* logits = (const float*)d_in[1];
  const int*   masks  = (const int*)d_in[2];
  const float* W1     = (const float*)d_in[3];
  const float* b1     = (const float*)d_in[4];
  const float* W2     = (const float*)d_in[5];
  const float* b2     = (const float*)d_in[6];
  float* out = (float*)d_out;

  // workspace layout (~105 MB):
  //   sel_e (256B) | sel_g (256B) | pad | xb 8MB | w1t 16MB | w2t 16MB | H 64MB
  char* ws = (char*)d_ws;
  int*   sel_e = (int*)ws;
  float* sel_g = (float*)(ws + 256);
  unsigned short* xb  = (unsigned short*)(ws + 1024);
  unsigned short* w1t = xb  + (size_t)B_SZ * L_SZ * D_SZ;
  unsigned short* w2t = w1t + (size_t)E_SZ * F_SZ * D_SZ;
  unsigned short* Hbuf = w2t + (size_t)E_SZ * D_SZ * F_SZ;

  gates_kernel<<<1, 64, 0, stream>>>(logits, masks, sel_e, sel_g);

  int n4 = (B_SZ * L_SZ * D_SZ) / 4;
  convert_f32_bf16<<<n4 / 256, 256, 0, stream>>>(x, xb, n4);

  // W1 [E][D][F] -> w1t [E][F][D]
  transpose_convert<<<dim3(F_SZ / 64, D_SZ / 64, E_SZ), 256, 0, stream>>>(W1, w1t, D_SZ, F_SZ);
  // W2 [E][F][D] -> w2t [E][D][F]
  transpose_convert<<<dim3(D_SZ / 64, F_SZ / 64, E_SZ), 256, 0, stream>>>(W2, w2t, F_SZ, D_SZ);

  moe_gemm1<<<dim3(F_SZ / 128, L_SZ / 128, P_SZ), 256, 0, stream>>>(xb, w1t, b1, sel_e, Hbuf);
  moe_gemm2<<<dim3(D_SZ / 128, L_SZ / 128, B_SZ), 256, 0, stream>>>(Hbuf, w2t, b2, sel_e, sel_g, out);
}